// Round 6
// baseline (202.411 us; speedup 1.0000x reference)
//
#include <hip/hip_runtime.h>
#include <math.h>

// Problem constants (S4Checkpointed): b=2, L=2048, d=768, n=16, r=48
#define BATCH 2
#define LSEQ  2048
#define DIM   768
#define NST   16
#define RDT   48
#define BL    (BATCH*LSEQ)   // 4096
#define NCHUNK 16
#define CLEN   (LSEQ/NCHUNK) // 128
#define CPAD   132           // chunk stride floats: 132%32==4 -> wave's 4 groups on distinct banks
#define CPAD4  (CPAD/4)      // 33
#define NPACK  (CLEN/4)      // 32 float4 packs per chunk
#define LP4    (LSEQ/4)      // 512 t-packs per (b)

// -------- Kernel A: sliced projection + x transpose ------------------------
// Only rows 0..15 (B), 32..47 (C), 1584..1631 (dt) of W_xproj are used.
// B/C written pack-transposed: float4[b][t/4][n] (component = t%4) -> scan
// loads coalesced. dt written (b, r, L). blockIdx.y==0 blocks also emit the
// x-tile transposed to xT (b,d,l) from LDS — replaces the input xpose kernel.
__global__ __launch_bounds__(256) void proj_kernel(
        const float* __restrict__ x, const float* __restrict__ Wx,
        float* __restrict__ Bpk, float* __restrict__ Cpk, float* __restrict__ dtpT,
        float* __restrict__ xT) {
    __shared__ float xs[16 * DIM];   // 48 KB
    const int bl0 = blockIdx.x * 16;
    const int tid = threadIdx.x;
    const float* xsrc = x + (size_t)bl0 * DIM;
    for (int i = tid; i < 16 * DIM / 4; i += 256)
        ((float4*)xs)[i] = ((const float4*)xsrc)[i];
    __syncthreads();

    // ---- x transpose: thread owns column d, writes one 64B line per row
    if (blockIdx.y == 0) {
        const int b  = bl0 >> 11;
        const int t0 = bl0 & 2047;
        for (int d = tid; d < DIM; d += 256) {
            float v[16];
            #pragma unroll
            for (int l = 0; l < 16; ++l) v[l] = xs[l * DIM + d];
            float4* dst = (float4*)(xT + ((size_t)(b * DIM + d)) * LSEQ + t0);
            dst[0] = make_float4(v[0], v[1], v[2], v[3]);
            dst[1] = make_float4(v[4], v[5], v[6], v[7]);
            dst[2] = make_float4(v[8], v[9], v[10], v[11]);
            dst[3] = make_float4(v[12], v[13], v[14], v[15]);
        }
    }

    const int wave = tid >> 6;
    const int lane = tid & 63;
    for (int jj = 0; jj < 5; ++jj) {
        const int j = blockIdx.y * 20 + wave * 5 + jj;   // 0..79
        const int row = (j < 16) ? j : ((j < 32) ? (j + 16) : (j + 1552));
        const float* wrow = Wx + (size_t)row * DIM;
        float w[12];
        #pragma unroll
        for (int i = 0; i < 12; ++i) w[i] = wrow[lane + i * 64];
        for (int l = 0; l < 16; ++l) {
            float s = 0.f;
            #pragma unroll
            for (int i = 0; i < 12; ++i) s += w[i] * xs[l * DIM + lane + i * 64];
            #pragma unroll
            for (int m = 32; m >= 1; m >>= 1) s += __shfl_xor(s, m, 64);
            if (lane == 0) {
                const int bl = bl0 + l;
                const int b  = bl >> 11;       // /2048
                const int t  = bl & 2047;
                const size_t pkidx = ((((size_t)(b * LP4 + (t >> 2)) * NST + ((j < 32) ? (j & 15) : 0)) << 2) | (t & 3));
                if (j < 16)       Bpk[pkidx] = s;
                else if (j < 32)  Cpk[pkidx] = s;
                else              dtpT[((size_t)(b * RDT + (j - 32))) * LSEQ + t] = s;
            }
        }
    }
}

// -------- Kernel T: 64x64 tiled transpose (b,R,C) -> (b,C,R) ---------------
__global__ __launch_bounds__(256) void xpose_kernel(
        const float* __restrict__ in, float* __restrict__ out, int R, int C) {
    __shared__ float tile[64][65];
    const int r0 = blockIdx.x * 64;
    const int c0 = blockIdx.y * 64;
    const int b  = blockIdx.z;
    const int tx = threadIdx.x & 63;
    const int ty = threadIdx.x >> 6;
    #pragma unroll
    for (int k = 0; k < 16; ++k) {
        const int r = ty * 16 + k;
        tile[r][tx] = in[((size_t)b * R + (r0 + r)) * C + c0 + tx];
    }
    __syncthreads();
    #pragma unroll
    for (int k = 0; k < 16; ++k) {
        const int r = ty * 16 + k;
        out[((size_t)b * C + (c0 + r)) * R + r0 + tx] = tile[tx][r];
    }
}

// -------- Kernel C: fused delta + chunked scan (pack-trick, Kogge-Stone) ----
// One block (256 thr, 4 waves) per (b,d): single-round residency (6 blocks/CU,
// LDS 19.6 KB, no block-round tail). 16 groups x 16 n-lanes; group g owns 128 t.
__global__ __launch_bounds__(256) void scan_kernel(
        const float* __restrict__ xT, const float* __restrict__ z,
        const float* __restrict__ A_log, const float* __restrict__ Dp,
        const float* __restrict__ Bpk, const float* __restrict__ Cpk,
        const float* __restrict__ dtpT, const float* __restrict__ Wdt,
        const float* __restrict__ bdt, float* __restrict__ yT) {
    __shared__ float sdel[NCHUNK * CPAD];   // 8448 B; phase 3 reuses as y buffer
    __shared__ float sx[NCHUNK * CPAD];     // 8448 B
    __shared__ float sP[NCHUNK][NST];       // 1 KB
    __shared__ float sq[NCHUNK][NST];       // 1 KB
    __shared__ float sw[RDT];

    const int tid = threadIdx.x;
    const int ch = blockIdx.x;           // b*768 + d
    const int b = ch / DIM;
    const int d = ch % DIM;
    const size_t row = (size_t)ch * LSEQ;

    // ---- phase 0a: stage x row (padded chunks) + Wdt row to LDS
    if (tid < RDT) sw[tid] = Wdt[(size_t)d * RDT + tid];
    {
        #pragma unroll
        for (int i = 0; i < 2; ++i) {
            const int idx = tid + 256 * i;               // float4 index 0..511
            const float4 xv4 = ((const float4*)(xT + row))[idx];
            ((float4*)sx)[(idx >> 5) * CPAD4 + (idx & 31)] = xv4;
        }
    }
    __syncthreads();

    // ---- phase 0b: fused delta -> sdel. Thread owns 2 float4 t-columns.
    {
        const float bb = 2.0f * bdt[d];
        const float* dbase = dtpT + (size_t)b * RDT * LSEQ;
        #pragma unroll
        for (int i = 0; i < 2; ++i) {
            const int idx = tid + 256 * i;
            float4 acc = make_float4(bb, bb, bb, bb);
            #pragma unroll 3
            for (int k4 = 0; k4 < RDT / 4; ++k4) {
                const float4 wv = ((const float4*)sw)[k4];
                #pragma unroll
                for (int j = 0; j < 4; ++j) {
                    const int k = k4 * 4 + j;
                    const float wk = (j == 0) ? wv.x : (j == 1) ? wv.y : (j == 2) ? wv.z : wv.w;
                    const float4 v = ((const float4*)(dbase + (size_t)k * LSEQ))[idx];
                    acc.x = fmaf(v.x, wk, acc.x);
                    acc.y = fmaf(v.y, wk, acc.y);
                    acc.z = fmaf(v.z, wk, acc.z);
                    acc.w = fmaf(v.w, wk, acc.w);
                }
            }
            float4 sp;
            sp.x = (acc.x > 20.f) ? acc.x : __logf(1.f + __expf(acc.x));
            sp.y = (acc.y > 20.f) ? acc.y : __logf(1.f + __expf(acc.y));
            sp.z = (acc.z > 20.f) ? acc.z : __logf(1.f + __expf(acc.z));
            sp.w = (acc.w > 20.f) ? acc.w : __logf(1.f + __expf(acc.w));
            ((float4*)sdel)[(idx >> 5) * CPAD4 + (idx & 31)] = sp;
        }
    }
    __syncthreads();

    const int g = tid >> 4;          // chunk 0..15
    const int n = tid & 15;          // state index
    const float Aln = -__expf(A_log[d * NST + n]);
    // pack-transposed base: float4 index (b*512 + g*32 + p)*16 + n
    const float4* Bg = (const float4*)Bpk + ((size_t)(b * LP4 + g * NPACK) * NST + n);
    const float4* Cg = (const float4*)Cpk + ((size_t)(b * LP4 + g * NPACK) * NST + n);
    const float* dchunk = sdel + g * CPAD;
    const float* xchunk = sx + g * CPAD;

    // ---- phase 1: local scan with pack trick (chain: 1 fma per 4t)
    {
        float h = 0.f, Ptot = 1.f;
        float4 Bn_ = Bg[0];
        #pragma unroll 4
        for (int p = 0; p < NPACK; ++p) {
            const float4 B4 = Bn_;
            if (p < NPACK - 1) Bn_ = Bg[(p + 1) * NST];
            const float4 dl = *(const float4*)(dchunk + 4 * p);
            const float4 xv = *(const float4*)(xchunk + 4 * p);
            const float u0 = dl.x * xv.x * B4.x, u1 = dl.y * xv.y * B4.y;
            const float u2 = dl.z * xv.z * B4.z, u3 = dl.w * xv.w * B4.w;
            const float e0  = __expf(Aln * dl.x), dA1 = __expf(Aln * dl.y);
            const float dA2 = __expf(Aln * dl.z), dA3 = __expf(Aln * dl.w);
            float s = u0;
            s = fmaf(dA1, s, u1); s = fmaf(dA2, s, u2); s = fmaf(dA3, s, u3);
            const float E3 = ((e0 * dA1) * (dA2 * dA3));
            h = fmaf(E3, h, s);          // the only cross-pack chain op
            Ptot *= E3;
        }
        sP[g][n] = Ptot;
        sq[g][n] = h;
    }
    __syncthreads();

    // ---- phase 2: Kogge-Stone inclusive scan of transforms over 16 chunks
    {
        float Pc = sP[g][n], qc = sq[g][n];
        #pragma unroll
        for (int s = 1; s < NCHUNK; s <<= 1) {
            float Pp = 1.f, qp = 0.f;
            if (g >= s) { Pp = sP[g - s][n]; qp = sq[g - s][n]; }
            __syncthreads();
            qc = fmaf(Pc, qp, qc);
            Pc *= Pp;
            sP[g][n] = Pc; sq[g][n] = qc;
            __syncthreads();
        }
    }

    // ---- phase 3: re-scan with carry; h_i independent given pack entry h
    {
        float h = (g == 0) ? 0.f : sq[g - 1][n];
        const float Dd = Dp[d];
        float* ybuf = sdel;              // reuse: pack p written after pack p read
        float4 Bn_ = Bg[0];
        float4 Cn_ = Cg[0];
        #pragma unroll 4
        for (int p = 0; p < NPACK; ++p) {
            const float4 B4 = Bn_, C4 = Cn_;
            if (p < NPACK - 1) { Bn_ = Bg[(p + 1) * NST]; Cn_ = Cg[(p + 1) * NST]; }
            const float4 dl = *(const float4*)(dchunk + 4 * p);
            const float4 xv = *(const float4*)(xchunk + 4 * p);
            const float u0 = dl.x * xv.x * B4.x, u1 = dl.y * xv.y * B4.y;
            const float u2 = dl.z * xv.z * B4.z, u3 = dl.w * xv.w * B4.w;
            const float E0  = __expf(Aln * dl.x), dA1 = __expf(Aln * dl.y);
            const float dA2 = __expf(Aln * dl.z), dA3 = __expf(Aln * dl.w);
            const float E1 = E0 * dA1, E2 = E1 * dA2, E3 = E2 * dA3;
            const float s0 = u0;
            const float s1 = fmaf(dA1, s0, u1);
            const float s2 = fmaf(dA2, s1, u2);
            const float s3 = fmaf(dA3, s2, u3);
            const float h0 = fmaf(E0, h, s0);
            const float h1 = fmaf(E1, h, s1);
            const float h2 = fmaf(E2, h, s2);
            const float h3 = fmaf(E3, h, s3);
            h = h3;                      // 1-fma cross-pack chain
            float p0 = h0 * C4.x, p1 = h1 * C4.y, p2 = h2 * C4.z, p3 = h3 * C4.w;
            p0 += __shfl_xor(p0, 1); p0 += __shfl_xor(p0, 2);
            p1 += __shfl_xor(p1, 1); p1 += __shfl_xor(p1, 2);
            p2 += __shfl_xor(p2, 1); p2 += __shfl_xor(p2, 2);
            p3 += __shfl_xor(p3, 1); p3 += __shfl_xor(p3, 2);
            float v = (n & 1) ? ((n & 2) ? p3 : p1) : ((n & 2) ? p2 : p0);
            v += __shfl_xor(v, 4);
            v += __shfl_xor(v, 8);
            if (n < 4) {                 // lane n holds total for t = 4p+n
                const float xvn = (n == 0) ? xv.x : (n == 1) ? xv.y : (n == 2) ? xv.z : xv.w;
                ybuf[g * CPAD + 4 * p + n] = fmaf(xvn, Dd, v);
            }
        }
    }
    __syncthreads();

    // ---- epilogue: y *= silu(z), write yT (aliases xT; x already consumed)
    {
        const float* zrow = z + row;
        float* yrow = yT + row;
        #pragma unroll
        for (int i = tid; i < LSEQ; i += 256) {
            const float zv = zrow[i];
            const float sig = 1.0f / (1.0f + __expf(-zv));
            yrow[i] = sdel[(i >> 7) * CPAD + (i & 127)] * zv * sig;
        }
    }
}

extern "C" void kernel_launch(void* const* d_in, const int* in_sizes, int n_in,
                              void* d_out, int out_size, void* d_ws, size_t ws_size,
                              hipStream_t stream) {
    const float* x     = (const float*)d_in[0];  // (2,2048,768)
    const float* z     = (const float*)d_in[1];  // (2,768,2048)
    const float* A_log = (const float*)d_in[2];  // (768,16)
    const float* D     = (const float*)d_in[3];  // (768,)
    const float* Wx    = (const float*)d_in[4];  // (1680,768)
    const float* Wdt   = (const float*)d_in[5];  // (768,48)
    const float* bdt   = (const float*)d_in[6];  // (768,)
    float* out = (float*)d_out;

    // ws layout (floats): Bpk[2*512*16*4] | Cpk[2*512*16*4] | dtpT[2*48*2048] | xT[2*768*2048]
    float* ws   = (float*)d_ws;
    float* Bpk  = ws;
    float* Cpk  = Bpk + (size_t)BATCH * LP4 * NST * 4;
    float* dtpT = Cpk + (size_t)BATCH * LP4 * NST * 4;
    float* xT   = dtpT + (size_t)BATCH * RDT * LSEQ;
    float* yT   = xT;   // alias: each block consumes its x row into LDS before writing y

    hipLaunchKernelGGL(proj_kernel, dim3(BL / 16, 4), dim3(256), 0, stream,
                       x, Wx, Bpk, Cpk, dtpT, xT);
    hipLaunchKernelGGL(scan_kernel, dim3(BATCH * DIM), dim3(256), 0, stream,
                       xT, z, A_log, D, Bpk, Cpk, dtpT, Wdt, bdt, yT);
    hipLaunchKernelGGL(xpose_kernel, dim3(DIM / 64, LSEQ / 64, BATCH), dim3(256), 0, stream,
                       yT, out, DIM, LSEQ);
}

// Round 7
// 154.600 us; speedup vs baseline: 1.3093x; 1.3093x over previous
//
#include <hip/hip_runtime.h>
#include <math.h>

// Problem constants (S4Checkpointed): b=2, L=2048, d=768, n=16, r=48
#define BATCH 2
#define LSEQ  2048
#define DIM   768
#define NST   16
#define RDT   48
#define BL    (BATCH*LSEQ)   // 4096
#define NCHUNK 32
#define CLEN   (LSEQ/NCHUNK) // 64
#define CPAD   68            // chunk stride floats: 68%32==4 -> wave's 4 groups on distinct banks
#define NPACK  (CLEN/4)      // 16 float4 packs per chunk
#define LP4    (LSEQ/4)      // 512 t-packs per (b)

typedef __attribute__((ext_vector_type(8))) short short8;     // 8 bf16 (4 VGPRs)
typedef __attribute__((ext_vector_type(4))) float float4e;    // MFMA acc

__device__ __forceinline__ ushort f2bf(float f) {
    union { float f; unsigned u; } v; v.f = f;
    unsigned u = v.u;
    u += 0x7fffu + ((u >> 16) & 1u);   // round-to-nearest-even
    return (ushort)(u >> 16);
}

// -------- Kernel P: pack x->bf16 + x transpose + pack W slice to bf16 ------
// grid (32, 13, 2): y<12 -> 64x64 tile of x (b, l=2048, d=768):
//   writes xbf (bf16, same layout) + xT (fp32, (b,d,l)).
// y==12 -> pack the 80 live W_xproj rows [B:0..15 | C:32..47 | dt:1584..1631]
//   into Wbf[80][768] bf16 (64 blocks grid-stride).
__global__ __launch_bounds__(256) void pack_kernel(
        const float* __restrict__ x, const float* __restrict__ Wx,
        ushort* __restrict__ xbf, float* __restrict__ xT,
        ushort* __restrict__ Wbf) {
    if (blockIdx.y == 12) {
        const int blk = blockIdx.z * 32 + blockIdx.x;       // 0..63
        for (int idx = blk * 256 + threadIdx.x; idx < 80 * DIM; idx += 64 * 256) {
            const int j = idx / DIM;
            const int k = idx - j * DIM;
            const int row = (j < 16) ? j : ((j < 32) ? (j + 16) : (j + 1552));
            Wbf[idx] = f2bf(Wx[(size_t)row * DIM + k]);
        }
        return;
    }
    __shared__ float tile[64][65];
    const int r0 = blockIdx.x * 64;     // l
    const int c0 = blockIdx.y * 64;     // d
    const int b  = blockIdx.z;
    const int tx = threadIdx.x & 63;
    const int ty = threadIdx.x >> 6;
    #pragma unroll
    for (int k = 0; k < 16; ++k) {
        const int r = ty * 16 + k;
        const size_t gidx = ((size_t)b * LSEQ + (r0 + r)) * DIM + c0 + tx;
        const float v = x[gidx];
        tile[r][tx] = v;
        xbf[gidx] = f2bf(v);
    }
    __syncthreads();
    #pragma unroll
    for (int k = 0; k < 16; ++k) {
        const int r = ty * 16 + k;
        xT[((size_t)b * DIM + (c0 + r)) * LSEQ + r0 + tx] = tile[tx][r];
    }
}

// -------- Kernel G: proj GEMM via MFMA -------------------------------------
// M=4096 (bl), N=80 (j: 16 B | 16 C | 48 dt), K=768. One wave per 16-row
// bl-tile; 5 N-tiles x 24 K-iters of mfma_f32_16x16x32_bf16.
// C/D layout: row = quad*4+reg, col = lane&15  ->  epilogue float4 stores
// land exactly on the pack-transposed Bpk/Cpk layout and dtpT rows.
__global__ __launch_bounds__(64) void proj_gemm_kernel(
        const ushort* __restrict__ xbf, const ushort* __restrict__ Wbf,
        float* __restrict__ Bpk, float* __restrict__ Cpk,
        float* __restrict__ dtpT) {
    const int m0   = blockIdx.x * 16;   // bl tile base (never straddles b)
    const int lane = threadIdx.x;       // 0..63
    const int col  = lane & 15;         // output col (j within tile) / A row
    const int quad = lane >> 4;

    const short* A  = (const short*)xbf + (size_t)(m0 + col) * DIM + quad * 8;
    const short* Bw = (const short*)Wbf;

    float4e acc[5] = {};
    #pragma unroll 6
    for (int kk = 0; kk < 24; ++kk) {
        const short8 a = *(const short8*)(A + kk * 32);
        #pragma unroll
        for (int nt = 0; nt < 5; ++nt) {
            const short8 bf = *(const short8*)(Bw + (size_t)(nt * 16 + col) * DIM + kk * 32 + quad * 8);
            acc[nt] = __builtin_amdgcn_mfma_f32_16x16x32_bf16(a, bf, acc[nt], 0, 0, 0);
        }
    }

    const int b  = m0 >> 11;
    const int t0 = m0 & 2047;
    // B (nt=0) and C (nt=1): float4 index (b*512 + t0/4 + quad)*16 + col
    const size_t pk4 = ((size_t)(b * LP4 + (t0 >> 2) + quad)) * NST + col;
    ((float4*)Bpk)[pk4] = *(float4*)&acc[0];
    ((float4*)Cpk)[pk4] = *(float4*)&acc[1];
    // dt (nt=2..4): r = (nt-2)*16+col; dtpT[(b*48+r)*2048 + t0+quad*4 ..+3]
    #pragma unroll
    for (int nt = 2; nt < 5; ++nt) {
        const int r = (nt - 2) * 16 + col;
        *(float4*)(dtpT + ((size_t)(b * RDT + r)) * LSEQ + t0 + quad * 4) = *(float4*)&acc[nt];
    }
}

// -------- Kernel T: 64x64 tiled transpose (b,R,C) -> (b,C,R) ---------------
__global__ __launch_bounds__(256) void xpose_kernel(
        const float* __restrict__ in, float* __restrict__ out, int R, int C) {
    __shared__ float tile[64][65];
    const int r0 = blockIdx.x * 64;
    const int c0 = blockIdx.y * 64;
    const int b  = blockIdx.z;
    const int tx = threadIdx.x & 63;
    const int ty = threadIdx.x >> 6;
    #pragma unroll
    for (int k = 0; k < 16; ++k) {
        const int r = ty * 16 + k;
        tile[r][tx] = in[((size_t)b * R + (r0 + r)) * C + c0 + tx];
    }
    __syncthreads();
    #pragma unroll
    for (int k = 0; k < 16; ++k) {
        const int r = ty * 16 + k;
        out[((size_t)b * C + (c0 + r)) * R + r0 + tx] = tile[tx][r];
    }
}

// -------- Kernel C: fused delta + chunked scan (pack-trick, Kogge-Stone) ----
// R5 proven config: one block (512 thr) per (b,d); 32 groups x 16 n-lanes.
__global__ __launch_bounds__(512) void scan_kernel(
        const float* __restrict__ xT, const float* __restrict__ z,
        const float* __restrict__ A_log, const float* __restrict__ Dp,
        const float* __restrict__ Bpk, const float* __restrict__ Cpk,
        const float* __restrict__ dtpT, const float* __restrict__ Wdt,
        const float* __restrict__ bdt, float* __restrict__ yT) {
    __shared__ float sdel[NCHUNK * CPAD];   // 8704 B; phase 3 reuses as y buffer
    __shared__ float sx[NCHUNK * CPAD];     // 8704 B
    __shared__ float sP[NCHUNK][NST];       // 2 KB
    __shared__ float sq[NCHUNK][NST];       // 2 KB
    __shared__ float sw[RDT];

    const int tid = threadIdx.x;
    const int ch = blockIdx.x;           // b*768 + d
    const int b = ch / DIM;
    const int d = ch % DIM;
    const size_t row = (size_t)ch * LSEQ;

    // ---- phase 0a: stage x row (padded chunks) + Wdt row to LDS
    if (tid < RDT) sw[tid] = Wdt[(size_t)d * RDT + tid];
    {
        const float4 xv4 = ((const float4*)(xT + row))[tid];
        ((float4*)sx)[(tid >> 4) * (CPAD / 4) + (tid & 15)] = xv4;
    }
    __syncthreads();

    // ---- phase 0b: fused delta -> sdel. Thread owns float4 t-column tid.
    {
        const float bb = 2.0f * bdt[d];
        const float* dbase = dtpT + (size_t)b * RDT * LSEQ;
        float4 acc = make_float4(bb, bb, bb, bb);
        #pragma unroll 3
        for (int k4 = 0; k4 < RDT / 4; ++k4) {
            const float4 wv = ((const float4*)sw)[k4];
            #pragma unroll
            for (int j = 0; j < 4; ++j) {
                const int k = k4 * 4 + j;
                const float wk = (j == 0) ? wv.x : (j == 1) ? wv.y : (j == 2) ? wv.z : wv.w;
                const float4 v = ((const float4*)(dbase + (size_t)k * LSEQ))[tid];
                acc.x = fmaf(v.x, wk, acc.x);
                acc.y = fmaf(v.y, wk, acc.y);
                acc.z = fmaf(v.z, wk, acc.z);
                acc.w = fmaf(v.w, wk, acc.w);
            }
        }
        float4 sp;
        sp.x = (acc.x > 20.f) ? acc.x : __logf(1.f + __expf(acc.x));
        sp.y = (acc.y > 20.f) ? acc.y : __logf(1.f + __expf(acc.y));
        sp.z = (acc.z > 20.f) ? acc.z : __logf(1.f + __expf(acc.z));
        sp.w = (acc.w > 20.f) ? acc.w : __logf(1.f + __expf(acc.w));
        ((float4*)sdel)[(tid >> 4) * (CPAD / 4) + (tid & 15)] = sp;
    }
    __syncthreads();

    const int g = tid >> 4;          // chunk 0..31
    const int n = tid & 15;          // state index
    const float Aln = -__expf(A_log[d * NST + n]);
    // pack-transposed base: float4 index (b*512 + g*16 + p)*16 + n
    const float4* Bg = (const float4*)Bpk + ((size_t)(b * LP4 + g * NPACK) * NST + n);
    const float4* Cg = (const float4*)Cpk + ((size_t)(b * LP4 + g * NPACK) * NST + n);
    const float* dchunk = sdel + g * CPAD;
    const float* xchunk = sx + g * CPAD;

    // ---- phase 1: local scan with pack trick (chain: 1 fma per 4t)
    {
        float h = 0.f, Ptot = 1.f;
        float4 Bn_ = Bg[0];
        #pragma unroll 4
        for (int p = 0; p < NPACK; ++p) {
            const float4 B4 = Bn_;
            if (p < NPACK - 1) Bn_ = Bg[(p + 1) * NST];
            const float4 dl = *(const float4*)(dchunk + 4 * p);
            const float4 xv = *(const float4*)(xchunk + 4 * p);
            const float u0 = dl.x * xv.x * B4.x, u1 = dl.y * xv.y * B4.y;
            const float u2 = dl.z * xv.z * B4.z, u3 = dl.w * xv.w * B4.w;
            const float e0  = __expf(Aln * dl.x), dA1 = __expf(Aln * dl.y);
            const float dA2 = __expf(Aln * dl.z), dA3 = __expf(Aln * dl.w);
            float s = u0;
            s = fmaf(dA1, s, u1); s = fmaf(dA2, s, u2); s = fmaf(dA3, s, u3);
            const float E3 = ((e0 * dA1) * (dA2 * dA3));
            h = fmaf(E3, h, s);          // the only cross-pack chain op
            Ptot *= E3;
        }
        sP[g][n] = Ptot;
        sq[g][n] = h;
    }
    __syncthreads();

    // ---- phase 2: Kogge-Stone inclusive scan of transforms over chunks
    {
        float Pc = sP[g][n], qc = sq[g][n];
        #pragma unroll
        for (int s = 1; s < NCHUNK; s <<= 1) {
            float Pp = 1.f, qp = 0.f;
            if (g >= s) { Pp = sP[g - s][n]; qp = sq[g - s][n]; }
            __syncthreads();
            qc = fmaf(Pc, qp, qc);
            Pc *= Pp;
            sP[g][n] = Pc; sq[g][n] = qc;
            __syncthreads();
        }
    }

    // ---- phase 3: re-scan with carry; h_i independent given pack entry h
    {
        float h = (g == 0) ? 0.f : sq[g - 1][n];
        const float Dd = Dp[d];
        float* ybuf = sdel;              // reuse: pack p written after pack p read
        float4 Bn_ = Bg[0];
        float4 Cn_ = Cg[0];
        #pragma unroll 4
        for (int p = 0; p < NPACK; ++p) {
            const float4 B4 = Bn_, C4 = Cn_;
            if (p < NPACK - 1) { Bn_ = Bg[(p + 1) * NST]; Cn_ = Cg[(p + 1) * NST]; }
            const float4 dl = *(const float4*)(dchunk + 4 * p);
            const float4 xv = *(const float4*)(xchunk + 4 * p);
            const float u0 = dl.x * xv.x * B4.x, u1 = dl.y * xv.y * B4.y;
            const float u2 = dl.z * xv.z * B4.z, u3 = dl.w * xv.w * B4.w;
            const float E0  = __expf(Aln * dl.x), dA1 = __expf(Aln * dl.y);
            const float dA2 = __expf(Aln * dl.z), dA3 = __expf(Aln * dl.w);
            const float E1 = E0 * dA1, E2 = E1 * dA2, E3 = E2 * dA3;
            const float s0 = u0;
            const float s1 = fmaf(dA1, s0, u1);
            const float s2 = fmaf(dA2, s1, u2);
            const float s3 = fmaf(dA3, s2, u3);
            const float h0 = fmaf(E0, h, s0);
            const float h1 = fmaf(E1, h, s1);
            const float h2 = fmaf(E2, h, s2);
            const float h3 = fmaf(E3, h, s3);
            h = h3;                      // 1-fma cross-pack chain
            float p0 = h0 * C4.x, p1 = h1 * C4.y, p2 = h2 * C4.z, p3 = h3 * C4.w;
            p0 += __shfl_xor(p0, 1); p0 += __shfl_xor(p0, 2);
            p1 += __shfl_xor(p1, 1); p1 += __shfl_xor(p1, 2);
            p2 += __shfl_xor(p2, 1); p2 += __shfl_xor(p2, 2);
            p3 += __shfl_xor(p3, 1); p3 += __shfl_xor(p3, 2);
            float v = (n & 1) ? ((n & 2) ? p3 : p1) : ((n & 2) ? p2 : p0);
            v += __shfl_xor(v, 4);
            v += __shfl_xor(v, 8);
            if (n < 4) {                 // lane n holds total for t = 4p+n
                const float xvn = (n == 0) ? xv.x : (n == 1) ? xv.y : (n == 2) ? xv.z : xv.w;
                ybuf[g * CPAD + 4 * p + n] = fmaf(xvn, Dd, v);
            }
        }
    }
    __syncthreads();

    // ---- epilogue: y *= silu(z), write yT (aliases xT; x already consumed)
    {
        const float* zrow = z + row;
        float* yrow = yT + row;
        #pragma unroll
        for (int i = tid; i < LSEQ; i += 512) {
            const float zv = zrow[i];
            const float sig = 1.0f / (1.0f + __expf(-zv));
            yrow[i] = sdel[(i >> 6) * CPAD + (i & 63)] * zv * sig;
        }
    }
}

extern "C" void kernel_launch(void* const* d_in, const int* in_sizes, int n_in,
                              void* d_out, int out_size, void* d_ws, size_t ws_size,
                              hipStream_t stream) {
    const float* x     = (const float*)d_in[0];  // (2,2048,768)
    const float* z     = (const float*)d_in[1];  // (2,768,2048)
    const float* A_log = (const float*)d_in[2];  // (768,16)
    const float* D     = (const float*)d_in[3];  // (768,)
    const float* Wx    = (const float*)d_in[4];  // (1680,768)
    const float* Wdt   = (const float*)d_in[5];  // (768,48)
    const float* bdt   = (const float*)d_in[6];  // (768,)
    float* out = (float*)d_out;

    // ws layout (floats):
    //   Bpk  [2*512*64]   =  65536
    //   Cpk  [2*512*64]   =  65536
    //   dtpT [2*48*2048]  = 196608
    //   xT   [2*768*2048] = 3145728  (scan writes yT over it)
    //   xbf  [2*2048*768] bf16 -> 1572864 float slots
    //   Wbf  [80*768]     bf16 ->   30720 float slots
    float* ws    = (float*)d_ws;
    float* Bpk   = ws;
    float* Cpk   = Bpk + (size_t)BATCH * LP4 * NST * 4;
    float* dtpT  = Cpk + (size_t)BATCH * LP4 * NST * 4;
    float* xT    = dtpT + (size_t)BATCH * RDT * LSEQ;
    float* yT    = xT;
    ushort* xbf  = (ushort*)(xT + (size_t)BATCH * DIM * LSEQ);
    ushort* Wbf  = xbf + (size_t)BATCH * LSEQ * DIM;

    hipLaunchKernelGGL(pack_kernel, dim3(LSEQ / 64, DIM / 64 + 1, BATCH), dim3(256), 0, stream,
                       x, Wx, xbf, xT, Wbf);
    hipLaunchKernelGGL(proj_gemm_kernel, dim3(BL / 16), dim3(64), 0, stream,
                       xbf, Wbf, Bpk, Cpk, dtpT);
    hipLaunchKernelGGL(scan_kernel, dim3(BATCH * DIM), dim3(512), 0, stream,
                       xT, z, A_log, D, Bpk, Cpk, dtpT, Wdt, bdt, yT);
    hipLaunchKernelGGL(xpose_kernel, dim3(DIM / 64, LSEQ / 64, BATCH), dim3(256), 0, stream,
                       yT, out, DIM, LSEQ);
}